// Round 1
// baseline (155.255 us; speedup 1.0000x reference)
//
#include <hip/hip_runtime.h>
#include <stdint.h>

// Problem constants
#define B_   128
#define C_   500
#define H_   16
#define P_   256      // 16*16 pixels per image
#define D_   192
#define C1O  300
#define H1   34
#define P1   (H1*H1)  // 1156
#define C2O  100
#define H2   36
#define P2   (H2*H2)  // 1296
#define C3O  3
#define H3   38
#define P3   (H3*H3)  // 1444
#define CROP 3
#define OW_  32
#define KTOP 30

__device__ __forceinline__ float sgnf(float v){ return (v > 0.f) ? 1.f : ((v < 0.f) ? -1.f : 0.f); }

// tap-validity pattern for a position in a length-36 conv output coming from a
// length-34 input with k=3, stride=1 transposed conv: which kh in [0,2] have
// valid input ih = oh-kh in [0,33].
__device__ __forceinline__ int pat36(int i){
  if (i == 0) return 0;       // {0}
  if (i == 1) return 1;       // {0,1}
  if (i <= 33) return 2;      // {0,1,2}
  if (i == 34) return 3;      // {1,2}
  return 4;                   // {2}
}

// ---------------------------------------------------------------- l1 / thr
__global__ void k_l1(const float* __restrict__ phi, const float* __restrict__ jumpp,
                     float* __restrict__ l1, float* __restrict__ thr){
  int c = blockIdx.x * blockDim.x + threadIdx.x;
  if (c >= C_) return;
  float s = 0.f;
  for (int d = 0; d < D_; ++d) s += fabsf(phi[d * C_ + c]);
  s += 1e-12f;
  l1[c] = s;
  thr[c] = jumpp[0] * s;   // |x| below this => quantizes to 0 regardless of mask
}

// ------------------------------------------------- base2 table [100][5][5]
// base2(o, pr, pc) = b2[o] + sum over valid taps of S[o][kh][kw],
// S[o][kh][kw] = sum_c w2[c][o][kh][kw] * relu(b1[c])
__global__ void k_base2(const float* __restrict__ w2, const float* __restrict__ b1,
                        const float* __restrict__ b2, float* __restrict__ tab){
  int o = blockIdx.x;        // 0..99
  int lane = threadIdx.x;    // 64 threads = 1 wave
  float acc[9] = {0,0,0,0,0,0,0,0,0};
  for (int c = lane; c < C1O; c += 64){
    float a1 = fmaxf(b1[c], 0.f);
    const float* w = w2 + (c * C2O + o) * 9;
#pragma unroll
    for (int t = 0; t < 9; ++t) acc[t] += w[t] * a1;
  }
#pragma unroll
  for (int t = 0; t < 9; ++t)
    for (int off = 32; off; off >>= 1) acc[t] += __shfl_down(acc[t], off);
  __shared__ float S[9];
  if (lane == 0){
#pragma unroll
    for (int t = 0; t < 9; ++t) S[t] = acc[t];
  }
  __syncthreads();
  if (lane < 25){
    const int lo[5] = {0,0,0,1,2}, hi[5] = {0,1,2,2,2};
    int pr = lane / 5, pc = lane % 5;
    float s = b2[o];
    for (int kh = lo[pr]; kh <= hi[pr]; ++kh)
      for (int kw = lo[pc]; kw <= hi[pc]; ++kw) s += S[kh * 3 + kw];
    tab[o * 25 + lane] = s;
  }
}

// ------------------------------------------------------- base3 [3][38][38]
__global__ void k_base3(const float* __restrict__ w3, const float* __restrict__ b3,
                        const float* __restrict__ tab, float* __restrict__ base3){
  int pix = blockIdx.x;            // 0..1443
  int oh = pix / H3, ow = pix % H3;
  int lane = threadIdx.x;          // 64
  float acc[3] = {0,0,0};
  for (int c = lane; c < C2O; c += 64){
    const float* w = w3 + c * 27;  // [c][o][kh][kw]
#pragma unroll
    for (int kh = 0; kh < 3; ++kh){
      int ih = oh - kh; if (ih < 0 || ih >= H2) continue;
      int prr = pat36(ih) * 5;
#pragma unroll
      for (int kw = 0; kw < 3; ++kw){
        int iw = ow - kw; if (iw < 0 || iw >= H2) continue;
        float a2 = fmaxf(tab[c * 25 + prr + pat36(iw)], 0.f);
#pragma unroll
        for (int o = 0; o < 3; ++o) acc[o] += w[o * 9 + kh * 3 + kw] * a2;
      }
    }
  }
#pragma unroll
  for (int o = 0; o < 3; ++o){
    for (int off = 32; off; off >>= 1) acc[o] += __shfl_down(acc[o], off);
  }
  if (lane == 0){
#pragma unroll
    for (int o = 0; o < 3; ++o) base3[o * P3 + pix] = acc[o] + b3[o];
  }
}

// ---------------------------------------- scan x, build dirty0 (+cold topk)
// Hot path: one pass over x, per-pixel flag = any(|x[c]| >= jump*l1[c]).
// Cold path (only if some pixel is flagged): exact top-30 (jax tie semantics:
// lower channel index wins) + saturation quantization into zq codes.
__global__ void k_zq(const float* __restrict__ x, const float* __restrict__ l1,
                     const float* __restrict__ thr, const float* __restrict__ jumpp,
                     signed char* __restrict__ zq, unsigned char* __restrict__ d0){
  int b = blockIdx.x >> 2;
  int tile = (blockIdx.x & 3) * 64;
  int t = threadIdx.x;               // 256
  int lane = t & 63, cg = t >> 6;    // 4 waves = 4 channel groups
  int p = tile + lane;
  int hot = 0;
#pragma unroll 4
  for (int c0 = 0; c0 < C_; c0 += 4){
    int c = c0 + cg;
    float v = x[(b * C_ + c) * P_ + p];
    hot |= (fabsf(v) >= thr[c]) ? 1 : 0;
  }
  __shared__ unsigned char shf[256];
  __shared__ unsigned char pixf[64];
  __shared__ int s_any;
  if (t == 0) s_any = 0;
  shf[t] = (unsigned char)hot;
  __syncthreads();
  if (t < 64){
    unsigned char f = shf[t] | shf[t + 64] | shf[t + 128] | shf[t + 192];
    pixf[t] = f;
    d0[b * P_ + tile + t] = f;
    if (f) s_any = 1;                // benign race, all write 1
  }
  __syncthreads();
  if (!s_any) return;

  // ---- cold path ----
  __shared__ float sx[C_];
  __shared__ unsigned char rm[C_];
  __shared__ unsigned long long red[4];
  __shared__ int sel[KTOP];
  float J = jumpp[0];
  for (int pp = 0; pp < 64; ++pp){
    if (!pixf[pp]) continue;
    int px = tile + pp;
    for (int c = t; c < C_; c += 256){ sx[c] = x[(b * C_ + c) * P_ + px]; rm[c] = 0; }
    __syncthreads();
    for (int it = 0; it < KTOP; ++it){
      unsigned long long best = 0ULL;
      for (int c = t; c < C_; c += 256){
        if (!rm[c]){
          unsigned long long key =
            ((unsigned long long)__float_as_uint(fabsf(sx[c])) << 32) |
            (unsigned int)(C_ - 1 - c);          // ties -> lower index wins
          if (key > best) best = key;
        }
      }
      for (int off = 32; off; off >>= 1){
        unsigned long long o2 = __shfl_down(best, off);
        if (o2 > best) best = o2;
      }
      if ((t & 63) == 0) red[t >> 6] = best;
      __syncthreads();
      if (t == 0){
        unsigned long long m = red[0];
        for (int wv = 1; wv < 4; ++wv) if (red[wv] > m) m = red[wv];
        int idx = C_ - 1 - (int)(m & 0xffffffffULL);
        sel[it] = idx;
        rm[idx] = 1;
      }
      __syncthreads();
    }
    for (int c = t; c < C_; c += 256) zq[(b * C_ + c) * P_ + px] = 0;
    __syncthreads();
    if (t < KTOP){
      int c = sel[t];
      float z = sx[c];
      float l = l1[c];
      float r = z / l;
      float q = 0.5f * (sgnf(r - J) + sgnf(r + J));   // in {-1,-0.5,0,0.5,1}
      int code = (int)(2.f * q);                      // exact: {-2,-1,0,1,2}
      if (code) zq[(b * C_ + c) * P_ + px] = (signed char)code;
    }
    __syncthreads();
  }
}

// ------------------------------------------- dirty1 propagation + worklist
__global__ void k_scan1(const unsigned char* __restrict__ d0, unsigned char* __restrict__ d1,
                        int* __restrict__ cnt, int* __restrict__ work1){
  int tid = blockIdx.x * blockDim.x + threadIdx.x;
  if (tid >= B_ * P1) return;
  int b = tid / P1, p1 = tid % P1;
  int ih = p1 / H1, iw = p1 % H1;
  int h0 = max(0, (ih - 2) >> 1), h1v = min(H_ - 1, ih >> 1);
  int w0 = max(0, (iw - 2) >> 1), w1v = min(H_ - 1, iw >> 1);
  int any = 0;
  for (int h = h0; h <= h1v; ++h)
    for (int w = w0; w <= w1v; ++w)
      any |= d0[b * P_ + h * H_ + w];
  if (any){ d1[tid] = 1; work1[atomicAdd(cnt, 1)] = tid; }
}

// -------------------------------------- u1 at dirty1 pixels (cold, sparse)
__global__ void k_u1(const signed char* __restrict__ zq, const float* __restrict__ l1,
                     const float* __restrict__ w1, const float* __restrict__ b1,
                     const unsigned char* __restrict__ d0,
                     const int* __restrict__ cnt, const int* __restrict__ work1,
                     float* __restrict__ u1, int have){
  int n = cnt[0];
  int lane = threadIdx.x;   // 64
  for (int i = blockIdx.x; i < n; i += gridDim.x){
    int tid = work1[i];
    int b = tid / P1, p1 = tid % P1;
    int ih = p1 / H1, iw = p1 % H1;
    float acc[5] = {0,0,0,0,0};
    int h0 = max(0, (ih - 2) >> 1), h1v = min(H_ - 1, ih >> 1);
    int w0 = max(0, (iw - 2) >> 1), w1v = min(H_ - 1, iw >> 1);
    for (int h = h0; h <= h1v; ++h)
      for (int w = w0; w <= w1v; ++w){
        if (!d0[b * P_ + h * H_ + w]) continue;
        int kh = ih - 2 * h, kw = iw - 2 * w;
        const signed char* zp = zq + (size_t)(b * C_) * P_ + h * H_ + w;
        for (int c = 0; c < C_; ++c){
          int code = zp[(size_t)c * P_];
          if (!code) continue;
          float val = 0.5f * (float)code * l1[c];
          const float* wp = w1 + (size_t)(c * C1O) * 16 + kh * 4 + kw;
#pragma unroll
          for (int j = 0; j < 5; ++j){
            int c1 = j * 64 + lane;
            if (c1 < C1O) acc[j] += wp[(size_t)c1 * 16] * val;
          }
        }
      }
    if (have){
#pragma unroll
      for (int j = 0; j < 5; ++j){
        int c1 = j * 64 + lane;
        if (c1 < C1O){
          float bb = b1[c1];
          u1[(size_t)(b * C1O + c1) * P1 + p1] = fmaxf(bb + acc[j], 0.f) - fmaxf(bb, 0.f);
        }
      }
    }
  }
}

// ------------------------------------------- dirty2 propagation + worklist
__global__ void k_scan2(const unsigned char* __restrict__ d1, unsigned char* __restrict__ d2,
                        int* __restrict__ cnt, int* __restrict__ work2){
  int tid = blockIdx.x * blockDim.x + threadIdx.x;
  if (tid >= B_ * P2) return;
  int b = tid / P2, p2 = tid % P2;
  int oh = p2 / H2, ow = p2 % H2;
  int any = 0;
  for (int kh = 0; kh < 3; ++kh){
    int ih = oh - kh; if (ih < 0 || ih >= H1) continue;
    for (int kw = 0; kw < 3; ++kw){
      int iw = ow - kw; if (iw < 0 || iw >= H1) continue;
      any |= d1[b * P1 + ih * H1 + iw];
    }
  }
  if (any){ d2[tid] = 1; work2[atomicAdd(cnt, 1)] = tid; }
}

// -------------------------------------- u2 at dirty2 pixels (cold, sparse)
__global__ void k_u2(const float* __restrict__ u1, const float* __restrict__ w2,
                     const float* __restrict__ tab, const unsigned char* __restrict__ d1,
                     const int* __restrict__ cnt, const int* __restrict__ work2,
                     float* __restrict__ u2, int have){
  int n = cnt[0];
  int lane = threadIdx.x;   // 64
  for (int i = blockIdx.x; i < n; i += gridDim.x){
    int tid = work2[i];
    int b = tid / P2, p2 = tid % P2;
    int oh = p2 / H2, ow = p2 % H2;
    float acc[2] = {0,0};
    for (int kh = 0; kh < 3; ++kh){
      int ih = oh - kh; if (ih < 0 || ih >= H1) continue;
      for (int kw = 0; kw < 3; ++kw){
        int iw = ow - kw; if (iw < 0 || iw >= H1) continue;
        if (!d1[b * P1 + ih * H1 + iw]) continue;
        const float* up = u1 + (size_t)(b * C1O) * P1 + ih * H1 + iw;
        const float* wb = w2 + kh * 3 + kw;
        for (int c1 = 0; c1 < C1O; ++c1){
          float uv = up[(size_t)c1 * P1];
          if (uv == 0.f) continue;
          const float* wp = wb + (size_t)(c1 * C2O) * 9;
#pragma unroll
          for (int j = 0; j < 2; ++j){
            int c2 = j * 64 + lane;
            if (c2 < C2O) acc[j] += wp[(size_t)c2 * 9] * uv;
          }
        }
      }
    }
    if (have){
      int pr = pat36(oh) * 5 + pat36(ow);
#pragma unroll
      for (int j = 0; j < 2; ++j){
        int c2 = j * 64 + lane;
        if (c2 < C2O){
          float bs = tab[c2 * 25 + pr];
          u2[(size_t)(b * C2O + c2) * P2 + p2] = fmaxf(bs + acc[j], 0.f) - fmaxf(bs, 0.f);
        }
      }
    }
  }
}

// ----------------------------------------------------------- final output
__global__ void k_out(const float* __restrict__ base3, const unsigned char* __restrict__ d2,
                      const float* __restrict__ u2, const float* __restrict__ w3,
                      float* __restrict__ out){
  int tid = blockIdx.x * blockDim.x + threadIdx.x;
  if (tid >= B_ * OW_ * OW_) return;
  int b = tid >> 10;
  int rc = tid & 1023;
  int r = rc >> 5, cc = rc & 31;
  int oh = r + CROP, ow = cc + CROP;   // in [3,34]: all 9 taps in-bounds
  int any = 0;
#pragma unroll
  for (int kh = 0; kh < 3; ++kh)
#pragma unroll
    for (int kw = 0; kw < 3; ++kw)
      any |= d2[b * P2 + (oh - kh) * H2 + (ow - kw)];
  if (!any){
#pragma unroll
    for (int o = 0; o < 3; ++o)
      out[((b * 3 + o) * OW_ + r) * OW_ + cc] = fmaxf(base3[o * P3 + oh * H3 + ow], 0.f);
    return;
  }
  float acc[3];
#pragma unroll
  for (int o = 0; o < 3; ++o) acc[o] = base3[o * P3 + oh * H3 + ow];
  for (int kh = 0; kh < 3; ++kh){
    int ih = oh - kh;
    for (int kw = 0; kw < 3; ++kw){
      int iw = ow - kw;
      if (!d2[b * P2 + ih * H2 + iw]) continue;
      const float* up = u2 + (size_t)(b * C2O) * P2 + ih * H2 + iw;
      const float* wb = w3 + kh * 3 + kw;
      for (int c2 = 0; c2 < C2O; ++c2){
        float uv = up[(size_t)c2 * P2];
        if (uv == 0.f) continue;
        const float* wp = wb + c2 * 27;
#pragma unroll
        for (int o = 0; o < 3; ++o) acc[o] += wp[o * 9] * uv;
      }
    }
  }
#pragma unroll
  for (int o = 0; o < 3; ++o)
    out[((b * 3 + o) * OW_ + r) * OW_ + cc] = fmaxf(acc[o], 0.f);
}

extern "C" void kernel_launch(void* const* d_in, const int* in_sizes, int n_in,
                              void* d_out, int out_size, void* d_ws, size_t ws_size,
                              hipStream_t stream){
  const float* x   = (const float*)d_in[0];
  const float* phi = (const float*)d_in[1];
  const float* jmp = (const float*)d_in[2];
  const float* w1  = (const float*)d_in[3];
  const float* b1  = (const float*)d_in[4];
  const float* w2  = (const float*)d_in[5];
  const float* b2  = (const float*)d_in[6];
  const float* w3  = (const float*)d_in[7];
  const float* b3  = (const float*)d_in[8];
  float* out = (float*)d_out;
  char* ws = (char*)d_ws;

  // workspace layout (bytes, 16B-aligned chunks)
  constexpr size_t OFF_L1  = 0;                                  // 500 f32
  constexpr size_t OFF_THR = OFF_L1  + 2048;                     // 500 f32
  constexpr size_t OFF_TAB = OFF_THR + 2048;                     // 2500 f32
  constexpr size_t OFF_B3  = OFF_TAB + 10240;                    // 4332 f32
  constexpr size_t OFF_D0  = OFF_B3  + 17344;                    // 32768 u8
  constexpr size_t OFF_D1  = OFF_D0  + (size_t)B_ * P_;          // 147968 u8
  constexpr size_t OFF_D2  = OFF_D1  + (size_t)B_ * P1;          // 165888 u8
  constexpr size_t OFF_CNT = OFF_D2  + (size_t)B_ * P2;          // 2 i32 (pad 64)
  constexpr size_t OFF_WK1 = OFF_CNT + 64;
  constexpr size_t OFF_WK2 = OFF_WK1 + (size_t)B_ * P1 * 4;
  constexpr size_t OFF_ZQ  = OFF_WK2 + (size_t)B_ * P2 * 4;      // i8 codes
  constexpr size_t OFF_U1  = OFF_ZQ  + (size_t)B_ * C_ * P_;
  constexpr size_t OFF_U2  = OFF_U1  + (size_t)B_ * C1O * P1 * 4;
  constexpr size_t TOTAL   = OFF_U2  + (size_t)B_ * C2O * P2 * 4;

  float* l1p  = (float*)(ws + OFF_L1);
  float* thrp = (float*)(ws + OFF_THR);
  float* tabp = (float*)(ws + OFF_TAB);
  float* b3p  = (float*)(ws + OFF_B3);
  unsigned char* d0p = (unsigned char*)(ws + OFF_D0);
  unsigned char* d1p = (unsigned char*)(ws + OFF_D1);
  unsigned char* d2p = (unsigned char*)(ws + OFF_D2);
  int* cnt1 = (int*)(ws + OFF_CNT);
  int* cnt2 = cnt1 + 1;
  int* wk1  = (int*)(ws + OFF_WK1);
  int* wk2  = (int*)(ws + OFF_WK2);
  signed char* zqp = (signed char*)(ws + OFF_ZQ);
  float* u1p = (float*)(ws + OFF_U1);
  float* u2p = (float*)(ws + OFF_U2);
  int have = (ws_size >= TOTAL) ? 1 : 0;

  // zero dirty1, dirty2, counters (contiguous region)
  hipMemsetAsync(ws + OFF_D1, 0, (size_t)B_ * P1 + (size_t)B_ * P2 + 64, stream);

  k_l1   <<<1, 512, 0, stream>>>(phi, jmp, l1p, thrp);
  k_base2<<<C2O, 64, 0, stream>>>(w2, b1, b2, tabp);
  k_base3<<<P3, 64, 0, stream>>>(w3, b3, tabp, b3p);
  k_zq   <<<B_ * 4, 256, 0, stream>>>(x, l1p, thrp, jmp, zqp, d0p);
  k_scan1<<<(B_ * P1 + 255) / 256, 256, 0, stream>>>(d0p, d1p, cnt1, wk1);
  k_u1   <<<1024, 64, 0, stream>>>(zqp, l1p, w1, b1, d0p, cnt1, wk1, u1p, have);
  k_scan2<<<(B_ * P2 + 255) / 256, 256, 0, stream>>>(d1p, d2p, cnt2, wk2);
  k_u2   <<<1024, 64, 0, stream>>>(u1p, w2, tabp, d1p, cnt2, wk2, u2p, have);
  k_out  <<<(B_ * OW_ * OW_ + 255) / 256, 256, 0, stream>>>(b3p, d2p, u2p, w3, out);
}